// Round 2
// baseline (1110.001 us; speedup 1.0000x reference)
//
#include <hip/hip_runtime.h>
#include <hip/hip_bf16.h>
#include <cstdint>
#include <cstddef>

typedef __bf16 bf16x8 __attribute__((ext_vector_type(8)));
typedef __bf16 bf16x4 __attribute__((ext_vector_type(4)));
typedef float  f32x4  __attribute__((ext_vector_type(4)));

#define NB 16
#define NH 12
#define NL2 512
#define NL 256
#define ND 768
#define NHH 384
#define NSMP 192      // NB*NH
#define NROW 1152     // NSMP*6
#define NK 1536       // 2*ND (GEMM K)
#define NCAT 3072     // both directions' gates

static __device__ __forceinline__ float sigm(float x){ return 1.0f/(1.0f+expf(-x)); }

// ---------------------------------------------------------------------------
// prep: fp32 -> bf16 weight conversion + bias fold
// ---------------------------------------------------------------------------
__global__ __launch_bounds__(256) void prep_kernel(
    const float* wihf, const float* wihr, const float* whhf, const float* whhr,
    const float* bihf, const float* bhhf, const float* bihr, const float* bhhr,
    __bf16* wcat, __bf16* whh, float* biasf)
{
  const int N0 = 3072*1536/4;   // wcat quads
  const int N1 = (2*1536*384)/4; // whh quads
  int tid = blockIdx.x*256 + threadIdx.x;
  if (tid < N0) {
    int e = tid*4;
    int n = e/1536, k = e - n*1536;
    const float* src = (n < 1536) ? (wihf + (size_t)n*1536 + k)
                                  : (wihr + (size_t)(n-1536)*1536 + k);
    float4 v = *(const float4*)src;
    bf16x4 o = {(__bf16)v.x,(__bf16)v.y,(__bf16)v.z,(__bf16)v.w};
    *(bf16x4*)(wcat + e) = o;
  } else if (tid < N0+N1) {
    int e = (tid-N0)*4;
    const float* src = (e < 589824) ? (whhf + e) : (whhr + (e-589824));
    float4 v = *(const float4*)src;
    bf16x4 o = {(__bf16)v.x,(__bf16)v.y,(__bf16)v.z,(__bf16)v.w};
    *(bf16x4*)(whh + e) = o;
  } else if (tid < N0+N1+768) {
    int e = (tid-N0-N1)*4;
    for (int u=0; u<4; ++u) {
      int n = e+u;
      biasf[n] = (n < 1536) ? (bihf[n]+bhhf[n]) : (bihr[n-1536]+bhhr[n-1536]);
    }
  }
}

// ---------------------------------------------------------------------------
// rowsum: per (b,h,row) masked sum over the diagonal quadrant's 256 cols
// ---------------------------------------------------------------------------
__global__ __launch_bounds__(64) void rowsum_kernel(
    const float* att, const int* sent, float* rowsum)
{
  int gb = blockIdx.x;          // bh*512 + r
  int r  = gb & 511;
  int bh = gb >> 9;
  int b  = bh / NH;
  int q  = r >> 8;              // 0: A quadrant, 1: B quadrant
  int cbase = q << 8;
  const float* row = att + ((size_t)bh*NL2 + r)*NL2 + cbase;
  const int*   sp  = sent + b*NL2 + cbase;
  int l = threadIdx.x;
  float4 v = ((const float4*)row)[l];
  int4  s4 = ((const int4*)sp)[l];
  float sum = (s4.x==102?1e-9f:v.x) + (s4.y==102?1e-9f:v.y)
            + (s4.z==102?1e-9f:v.z) + (s4.w==102?1e-9f:v.w);
  for (int off=32; off; off>>=1) sum += __shfl_xor(sum, off);
  if (l==0) rowsum[gb] = sum;
}

// ---------------------------------------------------------------------------
// master: argmax (first-max) per (b,h) per quadrant -> window indices + touched
// ---------------------------------------------------------------------------
__global__ __launch_bounds__(64) void master_kernel(
    const float* rowsum, int* idxbuf, unsigned int* touched)
{
  int bh = blockIdx.x;
  int b  = bh / NH;
  int l  = threadIdx.x;
  const float* rs = rowsum + (size_t)bh*NL2;
  for (int q=0; q<2; ++q) {
    float bv = -1e30f; int bi = 0;
    for (int rr=0; rr<4; ++rr) {
      int r = rr*64 + l;
      float v = rs[q*NL + r];
      if (v > bv) { bv = v; bi = r; }
    }
    for (int off=32; off; off>>=1) {
      float ov = __shfl_xor(bv, off);
      int   oi = __shfl_xor(bi, off);
      if (ov > bv || (ov == bv && oi < bi)) { bv = ov; bi = oi; }
    }
    if (l == 0) {
      int pos = bi;
      if (pos == 0) pos = 1;
      if (pos == NL-1) pos = NL-2;
      int ll = 3;
      if (pos - 3 <= 0) ll = pos - 1;
      int rr2 = 6 - ll;
      if (pos + rr2 >= NL-1) { int r2 = NL - pos - 2; ll = 6 - r2; }
      int start = pos - ll;
      for (int s=0; s<6; ++s) {
        int idx = q*NL + start + s;
        idxbuf[bh*12 + q*6 + s] = idx;
        atomicOr(&touched[b*NL2 + idx], 1u);
      }
    }
  }
}

// ---------------------------------------------------------------------------
// slide gather: build bf16 slide (1152 x 1536)
// ---------------------------------------------------------------------------
__global__ __launch_bounds__(192) void slide_kernel(
    const float* logits, const float* mask, const int* idxbuf,
    const unsigned int* touched, __bf16* slide)
{
  int m = blockIdx.x;          // ns*6 + t
  int t = m % 6, ns = m / 6, b = ns / NH;
  int l = threadIdx.x;         // 0..191
  int k = l*8;
  int half = (k >= ND) ? 1 : 0;
  int idx = idxbuf[ns*12 + half*6 + t];
  bool kill = touched[b*NL2+idx] && (mask[b*NL2+idx] == 0.0f);
  const float* src = logits + ((size_t)b*NL2 + idx)*ND + (k - half*ND);
  float4 v0 = ((const float4*)src)[0];
  float4 v1 = ((const float4*)src)[1];
  if (kill) {
    v0 = make_float4(1e-9f,1e-9f,1e-9f,1e-9f);
    v1 = v0;
  }
  bf16x8 o = {(__bf16)v0.x,(__bf16)v0.y,(__bf16)v0.z,(__bf16)v0.w,
              (__bf16)v1.x,(__bf16)v1.y,(__bf16)v1.z,(__bf16)v1.w};
  *(bf16x8*)(slide + (size_t)m*NK + k) = o;
}

// ---------------------------------------------------------------------------
// logits_rep: mean over 512 positions (with touched&mask masking)
// ---------------------------------------------------------------------------
__global__ __launch_bounds__(256) void lrep_kernel(
    const float* logits, const float* mask, const unsigned int* touched, float* lrep)
{
  int b = blockIdx.x;
  int c = threadIdx.x;
  float a0=0.f, a1=0.f, a2=0.f;
  for (int p=0; p<NL2; ++p) {
    bool kill = touched[b*NL2+p] && (mask[b*NL2+p] == 0.0f);
    const float* row = logits + ((size_t)b*NL2 + p)*ND;
    if (kill) { a0 += 1e-9f; a1 += 1e-9f; a2 += 1e-9f; }
    else { a0 += row[c]; a1 += row[c+256]; a2 += row[c+512]; }
  }
  lrep[b*ND + c]       = a0 * (1.0f/512.0f);
  lrep[b*ND + c + 256] = a1 * (1.0f/512.0f);
  lrep[b*ND + c + 512] = a2 * (1.0f/512.0f);
}

// ---------------------------------------------------------------------------
// big GEMM: gates_x = slide(1152x1536) @ wcat(3072x1536)^T + bias  (bf16 MFMA)
// m97-style 128x128 tile, 4 waves, 16x16x32 MFMA, reg-staged LDS
// ---------------------------------------------------------------------------
__global__ __launch_bounds__(256) void gemm_kernel(
    const __bf16* A, const __bf16* Bw, const float* bias, float* C)
{
  __shared__ __bf16 lA[128][40];   // +8 pad -> conflict-light b128 reads
  __shared__ __bf16 lB[128][40];
  int bid = blockIdx.x;
  int bm = bid % 9, bn = bid / 9;
  int m0 = bm*128, n0 = bn*128;
  int tid = threadIdx.x, lane = tid & 63, wave = tid >> 6;
  int wr = wave >> 1, wc = wave & 1;
  int srow = tid >> 1, sk = (tid & 1) * 16;
  int lr = lane & 15, lk = (lane >> 4) * 8;
  f32x4 acc[4][4] = {};
  for (int k0 = 0; k0 < NK; k0 += 32) {
    bf16x8 a0 = *(const bf16x8*)(A  + (size_t)(m0+srow)*NK + k0 + sk);
    bf16x8 a1 = *(const bf16x8*)(A  + (size_t)(m0+srow)*NK + k0 + sk + 8);
    bf16x8 b0 = *(const bf16x8*)(Bw + (size_t)(n0+srow)*NK + k0 + sk);
    bf16x8 b1 = *(const bf16x8*)(Bw + (size_t)(n0+srow)*NK + k0 + sk + 8);
    __syncthreads();                       // prev tile's reads done
    *(bf16x8*)&lA[srow][sk]   = a0;
    *(bf16x8*)&lA[srow][sk+8] = a1;
    *(bf16x8*)&lB[srow][sk]   = b0;
    *(bf16x8*)&lB[srow][sk+8] = b1;
    __syncthreads();                       // staged visible
    bf16x8 af[4], bf[4];
#pragma unroll
    for (int i=0;i<4;++i) af[i] = *(const bf16x8*)&lA[wr*64 + i*16 + lr][lk];
#pragma unroll
    for (int j=0;j<4;++j) bf[j] = *(const bf16x8*)&lB[wc*64 + j*16 + lr][lk];
#pragma unroll
    for (int i=0;i<4;++i)
#pragma unroll
      for (int j=0;j<4;++j)
        acc[i][j] = __builtin_amdgcn_mfma_f32_16x16x32_bf16(af[i], bf[j], acc[i][j], 0,0,0);
  }
#pragma unroll
  for (int i=0;i<4;++i)
#pragma unroll
    for (int j=0;j<4;++j)
#pragma unroll
      for (int r=0;r<4;++r) {
        int m = m0 + wr*64 + i*16 + (lane>>4)*4 + r;
        int n = n0 + wc*64 + j*16 + lr;
        C[(size_t)m*NCAT + n] = acc[i][j][r] + bias[n];
      }
}

// ---------------------------------------------------------------------------
// LSTM recurrent: 24 blocks = 2 dirs x 12 sample-tiles(16). 4 waves, each wave
// owns 96 hidden units (computes all 4 gates for them -> lane-local cell update)
// ---------------------------------------------------------------------------
__global__ __launch_bounds__(256,1) void lstm_kernel(
    const __bf16* whh, const float* gatesx, float* rep)
{
  int blk = blockIdx.x;
  int d = blk / 12, st = blk % 12;
  int tid = threadIdx.x, wave = tid >> 6, lane = tid & 63;
  int lr = lane & 15, lk4 = lane >> 4;
  int j0 = wave * 96;
  __shared__ __bf16 hlds[16][392];       // 384 + 8 pad
  for (int i = tid; i < 16*392; i += 256) ((__bf16*)hlds)[i] = (__bf16)0.0f;
  __syncthreads();

  float c_[6][4], hs[6][4];
#pragma unroll
  for (int s=0;s<6;++s)
#pragma unroll
    for (int r=0;r<4;++r) { c_[s][r]=0.f; hs[s][r]=0.f; }

  const __bf16* whd = whh + (size_t)d*1536*384;

  for (int step=0; step<6; ++step) {
    int t = d ? (5-step) : step;
    // A frags: h (16 samples x 384) from LDS
    bf16x8 af[12];
#pragma unroll
    for (int kk=0; kk<12; ++kk)
      af[kk] = *(const bf16x8*)&hlds[lr][kk*32 + lk4*8];
    __syncthreads();                     // all reads done before h overwrite

    // acc init from gates_x (includes x@W_ih^T + bias)
    f32x4 acc[4][6];
#pragma unroll
    for (int g=0; g<4; ++g)
#pragma unroll
      for (int s=0; s<6; ++s)
#pragma unroll
        for (int r=0; r<4; ++r) {
          int m = st*16 + lk4*4 + r;
          int col = d*1536 + g*384 + j0 + s*16 + lr;
          acc[g][s][r] = gatesx[(size_t)(m*6 + t)*NCAT + col];
        }
    // MFMA over K=384
#pragma unroll
    for (int kk=0; kk<12; ++kk) {
#pragma unroll
      for (int g=0; g<4; ++g)
#pragma unroll
        for (int s=0; s<6; ++s) {
          bf16x8 bfr = *(const bf16x8*)(whd + (size_t)(g*384 + j0 + s*16 + lr)*384 + kk*32 + lk4*8);
          acc[g][s] = __builtin_amdgcn_mfma_f32_16x16x32_bf16(af[kk], bfr, acc[g][s], 0,0,0);
        }
    }
    // cell update (lane-local across the 4 gate accs) + write new h
#pragma unroll
    for (int s=0; s<6; ++s)
#pragma unroll
      for (int r=0; r<4; ++r) {
        float gi = acc[0][s][r], gf = acc[1][s][r], gg = acc[2][s][r], go = acc[3][s][r];
        float cc = sigm(gf)*c_[s][r] + sigm(gi)*tanhf(gg);
        float hh = sigm(go)*tanhf(cc);
        c_[s][r] = cc;
        hs[s][r] += hh;
        hlds[lk4*4 + r][j0 + s*16 + lr] = (__bf16)hh;
      }
    __syncthreads();                     // writes visible for next step
  }

#pragma unroll
  for (int s=0; s<6; ++s)
#pragma unroll
    for (int r=0; r<4; ++r) {
      int m = st*16 + lk4*4 + r;
      rep[(size_t)m*ND + d*384 + j0 + s*16 + lr] = hs[s][r] * (1.0f/6.0f);
    }
}

// ---------------------------------------------------------------------------
// final: x = [rep.reshape(16,9216), lrep] @ fc_w^T + fc_b -> softmax
// ---------------------------------------------------------------------------
__global__ __launch_bounds__(256) void final_kernel(
    const float* rep, const float* lrep, const float* fcw, const float* fcb, float* out)
{
  __shared__ float zs[2][256];
  int b = blockIdx.x, t = threadIdx.x;
  float z0=0.f, z1=0.f;
  for (int i = t; i < 9984; i += 256) {
    float xv;
    if (i < 9216) { int h = i/768, j = i - h*768; xv = rep[(size_t)(b*NH + h)*ND + j]; }
    else          { xv = lrep[b*ND + (i - 9216)]; }
    z0 += xv * fcw[i];
    z1 += xv * fcw[9984 + i];
  }
  zs[0][t] = z0; zs[1][t] = z1;
  __syncthreads();
  if (t == 0) {
    float s0=0.f, s1=0.f;
    for (int i=0;i<256;++i) { s0 += zs[0][i]; s1 += zs[1][i]; }
    s0 += fcb[0]; s1 += fcb[1];
    float mx = fmaxf(s0, s1);
    float e0 = expf(s0-mx), e1 = expf(s1-mx);
    float den = e0 + e1;
    out[b*2+0] = e0/den;
    out[b*2+1] = e1/den;
  }
}

// ---------------------------------------------------------------------------
extern "C" void kernel_launch(void* const* d_in, const int* in_sizes, int n_in,
                              void* d_out, int out_size, void* d_ws, size_t ws_size,
                              hipStream_t stream)
{
  (void)in_sizes; (void)n_in; (void)out_size; (void)ws_size;
  const int*   sent   = (const int*)d_in[0];
  const float* att    = (const float*)d_in[1];
  const float* logits = (const float*)d_in[2];
  const float* mask   = (const float*)d_in[3];
  const float* wihf   = (const float*)d_in[4];
  const float* whhf   = (const float*)d_in[5];
  const float* bihf   = (const float*)d_in[6];
  const float* bhhf   = (const float*)d_in[7];
  const float* wihr   = (const float*)d_in[8];
  const float* whhr   = (const float*)d_in[9];
  const float* bihr   = (const float*)d_in[10];
  const float* bhhr   = (const float*)d_in[11];
  const float* fcw    = (const float*)d_in[12];
  const float* fcb    = (const float*)d_in[13];

  char* ws = (char*)d_ws;
  float*        rowsum  = (float*)(ws + 0);         // 393216 B
  int*          idxbuf  = (int*)(ws + 393216);      // 9216 B
  unsigned int* touched = (unsigned int*)(ws + 402432); // 32768 B
  float*        lrep    = (float*)(ws + 435200);    // 49152 B
  float*        rep     = (float*)(ws + 484352);    // 589824 B
  float*        biasf   = (float*)(ws + 1074176);   // 12288 B
  __bf16*       slide   = (__bf16*)(ws + 1086464);  // 3538944 B
  __bf16*       wcat    = (__bf16*)(ws + 4625408);  // 9437184 B
  __bf16*       whh     = (__bf16*)(ws + 14062592); // 2359296 B
  float*        gx      = (float*)(ws + 16421888);  // 14155776 B  (end ~30.6 MB)

  hipMemsetAsync(touched, 0, NB*NL2*sizeof(unsigned int), stream);
  prep_kernel<<<5763, 256, 0, stream>>>(wihf, wihr, whhf, whhr, bihf, bhhf, bihr, bhhr, wcat, whh, biasf);
  rowsum_kernel<<<NB*NH*NL2, 64, 0, stream>>>(att, sent, rowsum);
  master_kernel<<<NB*NH, 64, 0, stream>>>(rowsum, idxbuf, touched);
  slide_kernel<<<NROW, 192, 0, stream>>>(logits, mask, idxbuf, touched, slide);
  lrep_kernel<<<NB, 256, 0, stream>>>(logits, mask, touched, lrep);
  gemm_kernel<<<216, 256, 0, stream>>>(slide, wcat, biasf, gx);
  lstm_kernel<<<24, 256, 0, stream>>>(whh, gx, rep);
  final_kernel<<<NB, 256, 0, stream>>>(rep, lrep, fcw, fcb, (float*)d_out);
}

// Round 4
// 976.026 us; speedup vs baseline: 1.1373x; 1.1373x over previous
//
#include <hip/hip_runtime.h>
#include <hip/hip_bf16.h>
#include <cstdint>
#include <cstddef>

typedef __bf16 bf16x8 __attribute__((ext_vector_type(8)));
typedef __bf16 bf16x4 __attribute__((ext_vector_type(4)));
typedef float  f32x4  __attribute__((ext_vector_type(4)));

#define NB 16
#define NH 12
#define NL2 512
#define NL 256
#define ND 768
#define NHH 384
#define NSMP 192      // NB*NH
#define NROW 1152     // NSMP*6
#define NK 1536       // 2*ND (GEMM K)
#define NCAT 3072     // both directions' gates

// W_hh chunked layout: per dir, 48 chunks (g*12+kk), each 384 rows x 32 cols bf16,
// byte(r,c) = r*64 + ((c>>3) ^ ((r>>1)&3))*16 + (c&7)*2   (swizzle baked into global)
#define WCH_ELEMS 12288          // 384*32
#define WSLAB_ELEMS 589824       // 48*12288 per dir

static __device__ __forceinline__ float sigm(float x){ return 1.0f/(1.0f+expf(-x)); }

typedef const __attribute__((address_space(1))) unsigned int* gas1_t;
typedef __attribute__((address_space(3))) unsigned int* las3_t;

// ---------------------------------------------------------------------------
// prep: fp32 -> bf16 weight conversion + bias fold + W_hh chunk/swizzle layout
// ---------------------------------------------------------------------------
__global__ __launch_bounds__(256) void prep_kernel(
    const float* wihf, const float* wihr, const float* whhf, const float* whhr,
    const float* bihf, const float* bhhf, const float* bihr, const float* bhhr,
    __bf16* wcat, __bf16* whhl, float* biasf)
{
  const int N0 = 3072*1536/4;     // wcat quads
  const int NW = 2*48*1536;       // whh 16B slots (2 dirs x 48 chunks x 1536 slots)
  int tid = blockIdx.x*256 + threadIdx.x;
  if (tid < N0) {
    int e = tid*4;
    int n = e/1536, k = e - n*1536;
    const float* src = (n < 1536) ? (wihf + (size_t)n*1536 + k)
                                  : (wihr + (size_t)(n-1536)*1536 + k);
    float4 v = *(const float4*)src;
    bf16x4 o = {(__bf16)v.x,(__bf16)v.y,(__bf16)v.z,(__bf16)v.w};
    *(bf16x4*)(wcat + e) = o;
  } else if (tid < N0+NW) {
    int s = tid - N0;
    int d   = s / (48*1536);  s -= d*(48*1536);
    int cid = s / 1536;       s -= cid*1536;
    int r   = s >> 2;
    int sl  = s & 3;
    int c8  = sl ^ ((r>>1)&3);           // source col-slot stored at slot sl
    int g = cid/12, kk = cid - g*12;
    const float* wsrc = (d ? whhr : whhf) + (size_t)(g*384 + r)*384 + kk*32 + c8*8;
    float4 v0 = ((const float4*)wsrc)[0];
    float4 v1 = ((const float4*)wsrc)[1];
    bf16x8 o = {(__bf16)v0.x,(__bf16)v0.y,(__bf16)v0.z,(__bf16)v0.w,
                (__bf16)v1.x,(__bf16)v1.y,(__bf16)v1.z,(__bf16)v1.w};
    *(bf16x8*)(whhl + (size_t)d*WSLAB_ELEMS + cid*WCH_ELEMS + r*32 + sl*8) = o;
  } else if (tid < N0+NW+768) {
    int e = (tid-N0-NW)*4;
    for (int u=0; u<4; ++u) {
      int n = e+u;
      biasf[n] = (n < 1536) ? (bihf[n]+bhhf[n]) : (bihr[n-1536]+bhhr[n-1536]);
    }
  }
}

// ---------------------------------------------------------------------------
// rowsum: 4 rows per 256-thread block (one wave per row)
// ---------------------------------------------------------------------------
__global__ __launch_bounds__(256) void rowsum_kernel(
    const float* att, const int* sent, float* rowsum)
{
  int wave = threadIdx.x >> 6;
  int l    = threadIdx.x & 63;
  int gb = blockIdx.x*4 + wave;  // bh*512 + r
  int r  = gb & 511;
  int bh = gb >> 9;
  int b  = bh / NH;
  int q  = r >> 8;
  int cbase = q << 8;
  const float* row = att + ((size_t)bh*NL2 + r)*NL2 + cbase;
  const int*   sp  = sent + b*NL2 + cbase;
  float4 v = ((const float4*)row)[l];
  int4  s4 = ((const int4*)sp)[l];
  float sum = (s4.x==102?1e-9f:v.x) + (s4.y==102?1e-9f:v.y)
            + (s4.z==102?1e-9f:v.z) + (s4.w==102?1e-9f:v.w);
  for (int off=32; off; off>>=1) sum += __shfl_xor(sum, off);
  if (l==0) rowsum[gb] = sum;
}

// ---------------------------------------------------------------------------
// master: argmax (first-max) per (b,h) per quadrant -> window indices + touched
// ---------------------------------------------------------------------------
__global__ __launch_bounds__(64) void master_kernel(
    const float* rowsum, int* idxbuf, unsigned int* touched)
{
  int bh = blockIdx.x;
  int b  = bh / NH;
  int l  = threadIdx.x;
  const float* rs = rowsum + (size_t)bh*NL2;
  for (int q=0; q<2; ++q) {
    float bv = -1e30f; int bi = 0;
    for (int rr=0; rr<4; ++rr) {
      int r = rr*64 + l;
      float v = rs[q*NL + r];
      if (v > bv) { bv = v; bi = r; }
    }
    for (int off=32; off; off>>=1) {
      float ov = __shfl_xor(bv, off);
      int   oi = __shfl_xor(bi, off);
      if (ov > bv || (ov == bv && oi < bi)) { bv = ov; bi = oi; }
    }
    if (l == 0) {
      int pos = bi;
      if (pos == 0) pos = 1;
      if (pos == NL-1) pos = NL-2;
      int ll = 3;
      if (pos - 3 <= 0) ll = pos - 1;
      int rr2 = 6 - ll;
      if (pos + rr2 >= NL-1) { int r2 = NL - pos - 2; ll = 6 - r2; }
      int start = pos - ll;
      for (int s=0; s<6; ++s) {
        int idx = q*NL + start + s;
        idxbuf[bh*12 + q*6 + s] = idx;
        atomicOr(&touched[b*NL2 + idx], 1u);
      }
    }
  }
}

// ---------------------------------------------------------------------------
// slide gather: build bf16 slide (1152 x 1536)
// ---------------------------------------------------------------------------
__global__ __launch_bounds__(192) void slide_kernel(
    const float* logits, const float* mask, const int* idxbuf,
    const unsigned int* touched, __bf16* slide)
{
  int m = blockIdx.x;          // ns*6 + t
  int t = m % 6, ns = m / 6, b = ns / NH;
  int l = threadIdx.x;         // 0..191
  int k = l*8;
  int half = (k >= ND) ? 1 : 0;
  int idx = idxbuf[ns*12 + half*6 + t];
  bool kill = touched[b*NL2+idx] && (mask[b*NL2+idx] == 0.0f);
  const float* src = logits + ((size_t)b*NL2 + idx)*ND + (k - half*ND);
  float4 v0 = ((const float4*)src)[0];
  float4 v1 = ((const float4*)src)[1];
  if (kill) {
    v0 = make_float4(1e-9f,1e-9f,1e-9f,1e-9f);
    v1 = v0;
  }
  bf16x8 o = {(__bf16)v0.x,(__bf16)v0.y,(__bf16)v0.z,(__bf16)v0.w,
              (__bf16)v1.x,(__bf16)v1.y,(__bf16)v1.z,(__bf16)v1.w};
  *(bf16x8*)(slide + (size_t)m*NK + k) = o;
}

// ---------------------------------------------------------------------------
// logits_rep partial: 128 blocks = b x 8 position-groups of 64
// ---------------------------------------------------------------------------
__global__ __launch_bounds__(256) void lrep_kernel(
    const float* logits, const float* mask, const unsigned int* touched, float* partial)
{
  int blk = blockIdx.x;       // b*8 + pg
  int b = blk >> 3, pg = blk & 7;
  int c = threadIdx.x;
  float a0=0.f, a1=0.f, a2=0.f;
  int p0 = pg*64;
  for (int p=p0; p<p0+64; ++p) {
    bool kill = touched[b*NL2+p] && (mask[b*NL2+p] == 0.0f);
    const float* row = logits + ((size_t)b*NL2 + p)*ND;
    if (kill) { a0 += 1e-9f; a1 += 1e-9f; a2 += 1e-9f; }
    else { a0 += row[c]; a1 += row[c+256]; a2 += row[c+512]; }
  }
  partial[(size_t)blk*ND + c]       = a0;
  partial[(size_t)blk*ND + c + 256] = a1;
  partial[(size_t)blk*ND + c + 512] = a2;
}

// ---------------------------------------------------------------------------
// big GEMM: gates_x = slide(1152x1536) @ wcat(3072x1536)^T + bias  (bf16 MFMA)
// ---------------------------------------------------------------------------
__global__ __launch_bounds__(256) void gemm_kernel(
    const __bf16* A, const __bf16* Bw, const float* bias, float* C)
{
  __shared__ __bf16 lA[128][40];
  __shared__ __bf16 lB[128][40];
  int bid = blockIdx.x;
  int bm = bid % 9, bn = bid / 9;
  int m0 = bm*128, n0 = bn*128;
  int tid = threadIdx.x, lane = tid & 63, wave = tid >> 6;
  int wr = wave >> 1, wc = wave & 1;
  int srow = tid >> 1, sk = (tid & 1) * 16;
  int lr = lane & 15, lk = (lane >> 4) * 8;
  f32x4 acc[4][4] = {};
  for (int k0 = 0; k0 < NK; k0 += 32) {
    bf16x8 a0 = *(const bf16x8*)(A  + (size_t)(m0+srow)*NK + k0 + sk);
    bf16x8 a1 = *(const bf16x8*)(A  + (size_t)(m0+srow)*NK + k0 + sk + 8);
    bf16x8 b0 = *(const bf16x8*)(Bw + (size_t)(n0+srow)*NK + k0 + sk);
    bf16x8 b1 = *(const bf16x8*)(Bw + (size_t)(n0+srow)*NK + k0 + sk + 8);
    __syncthreads();
    *(bf16x8*)&lA[srow][sk]   = a0;
    *(bf16x8*)&lA[srow][sk+8] = a1;
    *(bf16x8*)&lB[srow][sk]   = b0;
    *(bf16x8*)&lB[srow][sk+8] = b1;
    __syncthreads();
    bf16x8 af[4], bf[4];
#pragma unroll
    for (int i=0;i<4;++i) af[i] = *(const bf16x8*)&lA[wr*64 + i*16 + lr][lk];
#pragma unroll
    for (int j=0;j<4;++j) bf[j] = *(const bf16x8*)&lB[wc*64 + j*16 + lr][lk];
#pragma unroll
    for (int i=0;i<4;++i)
#pragma unroll
      for (int j=0;j<4;++j)
        acc[i][j] = __builtin_amdgcn_mfma_f32_16x16x32_bf16(af[i], bf[j], acc[i][j], 0,0,0);
  }
#pragma unroll
  for (int i=0;i<4;++i)
#pragma unroll
    for (int j=0;j<4;++j)
#pragma unroll
      for (int r=0;r<4;++r) {
        int m = m0 + wr*64 + i*16 + (lane>>4)*4 + r;
        int n = n0 + wc*64 + j*16 + lr;
        C[(size_t)m*NCAT + n] = acc[i][j][r] + bias[n];
      }
}

// ---------------------------------------------------------------------------
// LSTM recurrent v2: weights streamed to LDS via global_load_lds, double-buffer
// 24 blocks = 2 dirs x 12 sample-tiles(16). 4 waves x 96 hidden each.
// ---------------------------------------------------------------------------
__global__ __launch_bounds__(256,1) void lstm_kernel(
    const __bf16* whhl, const float* gatesx, float* rep)
{
  __shared__ __align__(16) __bf16 wbuf[2][WCH_ELEMS];   // 2 x 24 KB
  __shared__ __align__(16) __bf16 hlds[16][392];        // 12.25 KB
  int blk = blockIdx.x;
  int d = blk / 12, st = blk % 12;
  int tid = threadIdx.x, wave = tid >> 6, lane = tid & 63;
  int lr = lane & 15, lk4 = lane >> 4;
  int j0 = wave * 96;
  const __bf16* wsl = whhl + (size_t)d*WSLAB_ELEMS;

  for (int i = tid; i < 16*392; i += 256) ((__bf16*)hlds)[i] = (__bf16)0.0f;

  float c_[6][4], hs[6][4];
#pragma unroll
  for (int s=0;s<6;++s)
#pragma unroll
    for (int r=0;r<4;++r) { c_[s][r]=0.f; hs[s][r]=0.f; }

  // stage chunk: 24576 B, per wave 6 segments of 1024 B (seg = j*4+wave)
  #define STAGE(cid, buf) do { \
    const __bf16* _src = wsl + (size_t)(cid)*WCH_ELEMS; \
    _Pragma("unroll") \
    for (int _j=0;_j<6;++_j){ \
      int _seg = _j*4 + wave; \
      __builtin_amdgcn_global_load_lds( \
        (gas1_t)(_src + _seg*512 + lane*8), \
        (las3_t)(&wbuf[buf][_seg*512]), 16, 0, 0); \
    } } while(0)

  STAGE(0, 0);
  __syncthreads();   // hlds zero-init visible

  for (int step=0; step<6; ++step) {
    int t = d ? (5-step) : step;
    bf16x8 af[12];
#pragma unroll
    for (int kk=0; kk<12; ++kk)
      af[kk] = *(const bf16x8*)&hlds[lr][kk*32 + lk4*8];

    f32x4 acc[4][6];
#pragma unroll
    for (int g=0; g<4; ++g)
#pragma unroll
      for (int s=0; s<6; ++s)
#pragma unroll
        for (int r=0; r<4; ++r) {
          int m = st*16 + lk4*4 + r;
          int col = d*1536 + g*384 + j0 + s*16 + lr;
          acc[g][s][r] = gatesx[(size_t)(m*6 + t)*NCAT + col];
        }

    for (int c=0; c<48; ++c) {
      int cc = step*48 + c;
      __syncthreads();                       // buf[(c+1)&1] readers (chunk c-1) done
      if (cc+1 < 288) {
        STAGE((c+1)%48, (c+1)&1);
        asm volatile("s_waitcnt vmcnt(6)" ::: "memory");   // chunk c landed
      } else {
        asm volatile("s_waitcnt vmcnt(0)" ::: "memory");
      }
      __syncthreads();                       // all waves' chunk-c segments visible
      int g = c/12, kk = c - g*12;
      const __bf16* wb = wbuf[c & 1];
#pragma unroll
      for (int s=0; s<6; ++s) {
        int r = j0 + s*16 + lr;
        bf16x8 bfr = *(const bf16x8*)(wb + r*32 + ((lk4 ^ ((r>>1)&3))*8));
        acc[g][s] = __builtin_amdgcn_mfma_f32_16x16x32_bf16(af[kk], bfr, acc[g][s], 0,0,0);
      }
    }

    // cell update + write new h
#pragma unroll
    for (int s=0; s<6; ++s)
#pragma unroll
      for (int r=0; r<4; ++r) {
        float gi = acc[0][s][r], gf = acc[1][s][r], gg = acc[2][s][r], go = acc[3][s][r];
        float cc2 = sigm(gf)*c_[s][r] + sigm(gi)*tanhf(gg);
        float hh = sigm(go)*tanhf(cc2);
        c_[s][r] = cc2;
        hs[s][r] += hh;
        hlds[lk4*4 + r][j0 + s*16 + lr] = (__bf16)hh;
      }
    __syncthreads();                         // h visible for next step's af reads
  }

#pragma unroll
  for (int s=0; s<6; ++s)
#pragma unroll
    for (int r=0; r<4; ++r) {
      int m = st*16 + lk4*4 + r;
      rep[(size_t)m*ND + d*384 + j0 + s*16 + lr] = hs[s][r] * (1.0f/6.0f);
    }
  #undef STAGE
}

// ---------------------------------------------------------------------------
// final: x = [rep.reshape(16,9216), lrep(from partials)] @ fc_w^T + fc_b -> softmax
// ---------------------------------------------------------------------------
__global__ __launch_bounds__(256) void final_kernel(
    const float* rep, const float* partial, const float* fcw, const float* fcb, float* out)
{
  __shared__ float zs[2][256];
  int b = blockIdx.x, t = threadIdx.x;
  float z0=0.f, z1=0.f;
  for (int i = t; i < 9984; i += 256) {
    float xv;
    if (i < 9216) { int h = i/768, j = i - h*768; xv = rep[(size_t)(b*NH + h)*ND + j]; }
    else {
      int c = i - 9216;
      float s = 0.f;
#pragma unroll
      for (int pg=0; pg<8; ++pg) s += partial[(size_t)(b*8+pg)*ND + c];
      xv = s * (1.0f/512.0f);
    }
    z0 += xv * fcw[i];
    z1 += xv * fcw[9984 + i];
  }
  zs[0][t] = z0; zs[1][t] = z1;
  __syncthreads();
  if (t == 0) {
    float s0=0.f, s1=0.f;
    for (int i=0;i<256;++i) { s0 += zs[0][i]; s1 += zs[1][i]; }
    s0 += fcb[0]; s1 += fcb[1];
    float mx = fmaxf(s0, s1);
    float e0 = expf(s0-mx), e1 = expf(s1-mx);
    float den = e0 + e1;
    out[b*2+0] = e0/den;
    out[b*2+1] = e1/den;
  }
}

// ---------------------------------------------------------------------------
extern "C" void kernel_launch(void* const* d_in, const int* in_sizes, int n_in,
                              void* d_out, int out_size, void* d_ws, size_t ws_size,
                              hipStream_t stream)
{
  (void)in_sizes; (void)n_in; (void)out_size; (void)ws_size;
  const int*   sent   = (const int*)d_in[0];
  const float* att    = (const float*)d_in[1];
  const float* logits = (const float*)d_in[2];
  const float* mask   = (const float*)d_in[3];
  const float* wihf   = (const float*)d_in[4];
  const float* whhf   = (const float*)d_in[5];
  const float* bihf   = (const float*)d_in[6];
  const float* bhhf   = (const float*)d_in[7];
  const float* wihr   = (const float*)d_in[8];
  const float* whhr   = (const float*)d_in[9];
  const float* bihr   = (const float*)d_in[10];
  const float* bhhr   = (const float*)d_in[11];
  const float* fcw    = (const float*)d_in[12];
  const float* fcb    = (const float*)d_in[13];

  char* ws = (char*)d_ws;
  float*        rowsum  = (float*)(ws + 0);             // 393216
  int*          idxbuf  = (int*)(ws + 393216);          // 9216
  unsigned int* touched = (unsigned int*)(ws + 402432); // 32768
  float*        partial = (float*)(ws + 435200);        // 393216 (16x8x768)
  float*        rep     = (float*)(ws + 828416);        // 589824
  float*        biasf   = (float*)(ws + 1418240);       // 12288
  __bf16*       slide   = (__bf16*)(ws + 1430528);      // 3538944
  __bf16*       wcat    = (__bf16*)(ws + 4969472);      // 9437184
  __bf16*       whhl    = (__bf16*)(ws + 14406656);     // 2359296 (chunked layout)
  float*        gx      = (float*)(ws + 16765952);      // 14155776 -> end ~30.9 MB

  hipMemsetAsync(touched, 0, NB*NL2*sizeof(unsigned int), stream);
  prep_kernel<<<5187, 256, 0, stream>>>(wihf, wihr, whhf, whhr, bihf, bhhf, bihr, bhhr, wcat, whhl, biasf);
  rowsum_kernel<<<NB*NH*NL2/4, 256, 0, stream>>>(att, sent, rowsum);
  master_kernel<<<NB*NH, 64, 0, stream>>>(rowsum, idxbuf, touched);
  slide_kernel<<<NROW, 192, 0, stream>>>(logits, mask, idxbuf, touched, slide);
  lrep_kernel<<<NB*8, 256, 0, stream>>>(logits, mask, touched, partial);
  gemm_kernel<<<216, 256, 0, stream>>>(slide, wcat, biasf, gx);
  lstm_kernel<<<24, 256, 0, stream>>>(whhl, gx, rep);
  final_kernel<<<NB, 256, 0, stream>>>(rep, partial, fcw, fcb, (float*)d_out);
}

// Round 8
// 477.871 us; speedup vs baseline: 2.3228x; 2.0424x over previous
//
#include <hip/hip_runtime.h>
#include <hip/hip_bf16.h>
#include <cstdint>
#include <cstddef>

typedef __bf16 bf16x8 __attribute__((ext_vector_type(8)));
typedef __bf16 bf16x4 __attribute__((ext_vector_type(4)));
typedef float  f32x4  __attribute__((ext_vector_type(4)));

#define NB 16
#define NH 12
#define NL2 512
#define NL 256
#define ND 768
#define NHH 384
#define NSMP 192      // NB*NH
#define NROW 1152     // NSMP*6
#define NK 1536       // 2*ND (GEMM K)
#define NCAT 3072     // both directions' gates

static __device__ __forceinline__ float sigm(float x){ return 1.0f/(1.0f+expf(-x)); }

typedef const __attribute__((address_space(1))) unsigned int* gas1_t;
typedef __attribute__((address_space(3))) unsigned int* las3_t;

// ---------------------------------------------------------------------------
// prep: fp32 -> bf16 weight conversion + bias fold + W_hh slice/swizzle layout
// W_hh layout: 24 slices (d*12+jsl), each 128 rows (w = g*32+jj) x 384 k.
// 16B slot sl within a row holds source k-slot (sl ^ (w&7))  [involution]
// ---------------------------------------------------------------------------
__global__ __launch_bounds__(256) void prep_kernel(
    const float* wihf, const float* wihr, const float* whhf, const float* whhr,
    const float* bihf, const float* bhhf, const float* bihr, const float* bhhr,
    __bf16* wcat, __bf16* whl2, float* biasf)
{
  const int N0 = 3072*1536/4;     // wcat quads
  const int NW = 2*12*128*48;     // whh 16B slots = 147456
  int tid = blockIdx.x*256 + threadIdx.x;
  if (tid < N0) {
    int e = tid*4;
    int n = e/1536, k = e - n*1536;
    const float* src = (n < 1536) ? (wihf + (size_t)n*1536 + k)
                                  : (wihr + (size_t)(n-1536)*1536 + k);
    float4 v = *(const float4*)src;
    bf16x4 o = {(__bf16)v.x,(__bf16)v.y,(__bf16)v.z,(__bf16)v.w};
    *(bf16x4*)(wcat + e) = o;
  } else if (tid < N0+NW) {
    int s = tid - N0;
    int d    = s / 73728;  s -= d*73728;       // 12*128*48
    int jsl  = s / 6144;   s -= jsl*6144;      // 128*48
    int w    = s / 48;
    int sl   = s - w*48;
    int srcks = sl ^ (w & 7);
    int g = w >> 5, jj = w & 31;
    const float* wsrc = (d ? whhr : whhf) + (size_t)(g*384 + jsl*32 + jj)*384 + srcks*8;
    float4 v0 = ((const float4*)wsrc)[0];
    float4 v1 = ((const float4*)wsrc)[1];
    bf16x8 o = {(__bf16)v0.x,(__bf16)v0.y,(__bf16)v0.z,(__bf16)v0.w,
                (__bf16)v1.x,(__bf16)v1.y,(__bf16)v1.z,(__bf16)v1.w};
    *(bf16x8*)(whl2 + ((size_t)((d*12 + jsl)*128 + w))*384 + sl*8) = o;
  } else if (tid < N0+NW+768) {
    int e = (tid-N0-NW)*4;
    for (int u=0; u<4; ++u) {
      int n = e+u;
      biasf[n] = (n < 1536) ? (bihf[n]+bhhf[n]) : (bihr[n-1536]+bhhr[n-1536]);
    }
  }
}

// ---------------------------------------------------------------------------
// rowsum: grid-strided, 12 rows per wave, 2048 blocks x 4 waves
// ---------------------------------------------------------------------------
__global__ __launch_bounds__(256) void rowsum_kernel(
    const float* att, const int* sent, float* rowsum)
{
  int wave = threadIdx.x >> 6;
  int l    = threadIdx.x & 63;
  int wid  = blockIdx.x*4 + wave;       // 0..8191
#pragma unroll 4
  for (int i=0; i<12; ++i) {
    int gb = wid*12 + i;                // bh*512 + r, 0..98303
    int r  = gb & 511;
    int bh = gb >> 9;
    int b  = bh / NH;
    int q  = r >> 8;
    int cbase = q << 8;
    const float* row = att + ((size_t)bh*NL2 + r)*NL2 + cbase;
    const int*   sp  = sent + b*NL2 + cbase;
    float4 v = ((const float4*)row)[l];
    int4  s4 = ((const int4*)sp)[l];
    float sum = (s4.x==102?1e-9f:v.x) + (s4.y==102?1e-9f:v.y)
              + (s4.z==102?1e-9f:v.z) + (s4.w==102?1e-9f:v.w);
    for (int off=32; off; off>>=1) sum += __shfl_xor(sum, off);
    if (l==0) rowsum[gb] = sum;
  }
}

// ---------------------------------------------------------------------------
// master: argmax (first-max) per (b,h) per quadrant -> window indices + touched
// ---------------------------------------------------------------------------
__global__ __launch_bounds__(64) void master_kernel(
    const float* rowsum, int* idxbuf, unsigned int* touched)
{
  int bh = blockIdx.x;
  int b  = bh / NH;
  int l  = threadIdx.x;
  const float* rs = rowsum + (size_t)bh*NL2;
  for (int q=0; q<2; ++q) {
    float bv = -1e30f; int bi = 0;
    for (int rr=0; rr<4; ++rr) {
      int r = rr*64 + l;
      float v = rs[q*NL + r];
      if (v > bv) { bv = v; bi = r; }
    }
    for (int off=32; off; off>>=1) {
      float ov = __shfl_xor(bv, off);
      int   oi = __shfl_xor(bi, off);
      if (ov > bv || (ov == bv && oi < bi)) { bv = ov; bi = oi; }
    }
    if (l == 0) {
      int pos = bi;
      if (pos == 0) pos = 1;
      if (pos == NL-1) pos = NL-2;
      int ll = 3;
      if (pos - 3 <= 0) ll = pos - 1;
      int rr2 = 6 - ll;
      if (pos + rr2 >= NL-1) { int r2 = NL - pos - 2; ll = 6 - r2; }
      int start = pos - ll;
      for (int s=0; s<6; ++s) {
        int idx = q*NL + start + s;
        idxbuf[bh*12 + q*6 + s] = idx;
        atomicOr(&touched[b*NL2 + idx], 1u);
      }
    }
  }
}

// ---------------------------------------------------------------------------
// slide gather: build bf16 slide (1152 x 1536)
// ---------------------------------------------------------------------------
__global__ __launch_bounds__(192) void slide_kernel(
    const float* logits, const float* mask, const int* idxbuf,
    const unsigned int* touched, __bf16* slide)
{
  int m = blockIdx.x;          // ns*6 + t
  int t = m % 6, ns = m / 6, b = ns / NH;
  int l = threadIdx.x;         // 0..191
  int k = l*8;
  int half = (k >= ND) ? 1 : 0;
  int idx = idxbuf[ns*12 + half*6 + t];
  bool kill = touched[b*NL2+idx] && (mask[b*NL2+idx] == 0.0f);
  const float* src = logits + ((size_t)b*NL2 + idx)*ND + (k - half*ND);
  float4 v0 = ((const float4*)src)[0];
  float4 v1 = ((const float4*)src)[1];
  if (kill) {
    v0 = make_float4(1e-9f,1e-9f,1e-9f,1e-9f);
    v1 = v0;
  }
  bf16x8 o = {(__bf16)v0.x,(__bf16)v0.y,(__bf16)v0.z,(__bf16)v0.w,
              (__bf16)v1.x,(__bf16)v1.y,(__bf16)v1.z,(__bf16)v1.w};
  *(bf16x8*)(slide + (size_t)m*NK + k) = o;
}

// ---------------------------------------------------------------------------
// logits_rep partial: 128 blocks = b x 8 position-groups of 64
// ---------------------------------------------------------------------------
__global__ __launch_bounds__(256) void lrep_kernel(
    const float* logits, const float* mask, const unsigned int* touched, float* partial)
{
  int blk = blockIdx.x;       // b*8 + pg
  int b = blk >> 3, pg = blk & 7;
  int c = threadIdx.x;
  float a0=0.f, a1=0.f, a2=0.f;
  int p0 = pg*64;
  for (int p=p0; p<p0+64; ++p) {
    bool kill = touched[b*NL2+p] && (mask[b*NL2+p] == 0.0f);
    const float* row = logits + ((size_t)b*NL2 + p)*ND;
    if (kill) { a0 += 1e-9f; a1 += 1e-9f; a2 += 1e-9f; }
    else { a0 += row[c]; a1 += row[c+256]; a2 += row[c+512]; }
  }
  partial[(size_t)blk*ND + c]       = a0;
  partial[(size_t)blk*ND + c + 256] = a1;
  partial[(size_t)blk*ND + c + 512] = a2;
}

// ---------------------------------------------------------------------------
// big GEMM: gates_x = slide(1152x1536) @ wcat(3072x1536)^T + bias  (bf16 MFMA)
// ---------------------------------------------------------------------------
__global__ __launch_bounds__(256) void gemm_kernel(
    const __bf16* A, const __bf16* Bw, const float* bias, float* C)
{
  __shared__ __bf16 lA[128][40];
  __shared__ __bf16 lB[128][40];
  int bid = blockIdx.x;
  int bm = bid % 9, bn = bid / 9;
  int m0 = bm*128, n0 = bn*128;
  int tid = threadIdx.x, lane = tid & 63, wave = tid >> 6;
  int wr = wave >> 1, wc = wave & 1;
  int srow = tid >> 1, sk = (tid & 1) * 16;
  int lr = lane & 15, lk = (lane >> 4) * 8;
  f32x4 acc[4][4] = {};
  for (int k0 = 0; k0 < NK; k0 += 32) {
    bf16x8 a0 = *(const bf16x8*)(A  + (size_t)(m0+srow)*NK + k0 + sk);
    bf16x8 a1 = *(const bf16x8*)(A  + (size_t)(m0+srow)*NK + k0 + sk + 8);
    bf16x8 b0 = *(const bf16x8*)(Bw + (size_t)(n0+srow)*NK + k0 + sk);
    bf16x8 b1 = *(const bf16x8*)(Bw + (size_t)(n0+srow)*NK + k0 + sk + 8);
    __syncthreads();
    *(bf16x8*)&lA[srow][sk]   = a0;
    *(bf16x8*)&lA[srow][sk+8] = a1;
    *(bf16x8*)&lB[srow][sk]   = b0;
    *(bf16x8*)&lB[srow][sk+8] = b1;
    __syncthreads();
    bf16x8 af[4], bf[4];
#pragma unroll
    for (int i=0;i<4;++i) af[i] = *(const bf16x8*)&lA[wr*64 + i*16 + lr][lk];
#pragma unroll
    for (int j=0;j<4;++j) bf[j] = *(const bf16x8*)&lB[wc*64 + j*16 + lr][lk];
#pragma unroll
    for (int i=0;i<4;++i)
#pragma unroll
      for (int j=0;j<4;++j)
        acc[i][j] = __builtin_amdgcn_mfma_f32_16x16x32_bf16(af[i], bf[j], acc[i][j], 0,0,0);
  }
#pragma unroll
  for (int i=0;i<4;++i)
#pragma unroll
    for (int j=0;j<4;++j)
#pragma unroll
      for (int r=0;r<4;++r) {
        int m = m0 + wr*64 + i*16 + (lane>>4)*4 + r;
        int n = n0 + wc*64 + j*16 + lr;
        C[(size_t)m*NCAT + n] = acc[i][j][r] + bias[n];
      }
}

// ---------------------------------------------------------------------------
// LSTM step 0: h=0 so gates = gates_x; pure elementwise. One thread per (d,m,j).
// ---------------------------------------------------------------------------
__global__ __launch_bounds__(256) void lstm_step0_kernel(
    const float* gatesx, __bf16* hout, float* cbuf, float* hsbuf)
{
  int id = blockIdx.x*256 + threadIdx.x;     // 0..147455
  int d = id / 73728; int rem = id - d*73728;
  int m = rem / 384;  int j = rem - m*384;
  int t = d ? 5 : 0;
  const float* gr = gatesx + (size_t)(m*6 + t)*NCAT + d*1536;
  float gi = gr[j], gf = gr[384+j], gg = gr[768+j], go = gr[1152+j];
  (void)gf;  // c0 = 0 -> forget term vanishes
  float cc = sigm(gi)*tanhf(gg);
  float hh = sigm(go)*tanhf(cc);
  size_t ix = (size_t)(d*192+m)*384 + j;
  cbuf[ix] = cc; hsbuf[ix] = hh; hout[ix] = (__bf16)hh;
}

// ---------------------------------------------------------------------------
// LSTM step t (1..5): 48 blocks = d(2) x jsl(12) x mh(2).
// Block: M=96 samples, N=128 W-rows (4 gates x 32 hidden units), K=384.
// Weights resident in LDS (98 KB, staged once); h read from global (L2-hot).
// Waves 2x2: wave = (mw = wave>>1) x (jhalf = wave&1): M=48, N=64 (4g x 16jj).
// ---------------------------------------------------------------------------
__global__ __launch_bounds__(256,1) void lstm_step_kernel(
    const __bf16* whl2, const float* gatesx, const __bf16* hin, __bf16* hout,
    float* cbuf, float* hsbuf, float* rep, int step)
{
  __shared__ __align__(16) __bf16 wtile[128*384];   // 98304 B
  int blk = blockIdx.x;
  int d   = blk / 24;
  int rem = blk - d*24;
  int jsl = rem >> 1;
  int mh  = rem & 1;
  int tid = threadIdx.x, wave = tid>>6, lane = tid&63;
  int mw = wave>>1, jhalf = wave&1;
  int lr = lane&15, hi = lane>>4;

  // stage weight slice linearly: 24 rounds x 4096 B
  const __bf16* wsrc = whl2 + (size_t)(d*12 + jsl)*128*384;
#pragma unroll
  for (int rnd=0; rnd<24; ++rnd)
    __builtin_amdgcn_global_load_lds((gas1_t)(wsrc + rnd*2048 + tid*8),
                                     (las3_t)(wtile + rnd*2048 + tid*8), 16, 0, 0);

  int t = d ? (5-step) : step;
  f32x4 acc[3][4];
#pragma unroll
  for (int mt=0; mt<3; ++mt)
#pragma unroll
    for (int g=0; g<4; ++g)
#pragma unroll
      for (int r=0; r<4; ++r) {
        int m = mh*96 + mw*48 + mt*16 + hi*4 + r;
        int col = d*1536 + g*384 + jsl*32 + jhalf*16 + lr;
        acc[mt][g][r] = gatesx[(size_t)(m*6 + t)*NCAT + col];
      }
  __syncthreads();       // drains vmcnt -> weights + acc loads complete

  const __bf16* hbase = hin + (size_t)d*192*384;
#pragma unroll
  for (int kk=0; kk<12; ++kk) {
    bf16x8 a[3];
#pragma unroll
    for (int mt=0; mt<3; ++mt) {
      int m = mh*96 + mw*48 + mt*16 + lr;
      a[mt] = *(const bf16x8*)(hbase + (size_t)m*384 + kk*32 + hi*8);
    }
#pragma unroll
    for (int g=0; g<4; ++g) {
      int w = g*32 + jhalf*16 + lr;
      int ks = kk*4 + hi;
      bf16x8 b = *(const bf16x8*)(wtile + (size_t)w*384 + ((ks ^ (w&7))*8));
#pragma unroll
      for (int mt=0; mt<3; ++mt)
        acc[mt][g] = __builtin_amdgcn_mfma_f32_16x16x32_bf16(a[mt], b, acc[mt][g], 0,0,0);
    }
  }

  bool last = (step == 5);
#pragma unroll
  for (int mt=0; mt<3; ++mt)
#pragma unroll
    for (int r=0; r<4; ++r) {
      int m = mh*96 + mw*48 + mt*16 + hi*4 + r;
      int j = jsl*32 + jhalf*16 + lr;
      size_t ix = (size_t)(d*192 + m)*384 + j;
      float gi = acc[mt][0][r], gf = acc[mt][1][r], gg = acc[mt][2][r], go = acc[mt][3][r];
      float cc = sigm(gf)*cbuf[ix] + sigm(gi)*tanhf(gg);
      float hh = sigm(go)*tanhf(cc);
      float hsv = hsbuf[ix] + hh;
      if (last) {
        rep[(size_t)m*ND + d*384 + j] = hsv * (1.0f/6.0f);
      } else {
        cbuf[ix]  = cc;
        hsbuf[ix] = hsv;
        hout[ix]  = (__bf16)hh;
      }
    }
}

// ---------------------------------------------------------------------------
// final: x = [rep.reshape(16,9216), lrep(from partials)] @ fc_w^T + fc_b -> softmax
// ---------------------------------------------------------------------------
__global__ __launch_bounds__(256) void final_kernel(
    const float* rep, const float* partial, const float* fcw, const float* fcb, float* out)
{
  __shared__ float zs[2][256];
  int b = blockIdx.x, t = threadIdx.x;
  float z0=0.f, z1=0.f;
  for (int i = t; i < 9984; i += 256) {
    float xv;
    if (i < 9216) { int h = i/768, j = i - h*768; xv = rep[(size_t)(b*NH + h)*ND + j]; }
    else {
      int c = i - 9216;
      float s = 0.f;
#pragma unroll
      for (int pg=0; pg<8; ++pg) s += partial[(size_t)(b*8+pg)*ND + c];
      xv = s * (1.0f/512.0f);
    }
    z0 += xv * fcw[i];
    z1 += xv * fcw[9984 + i];
  }
  zs[0][t] = z0; zs[1][t] = z1;
  __syncthreads();
  if (t == 0) {
    float s0=0.f, s1=0.f;
    for (int i=0;i<256;++i) { s0 += zs[0][i]; s1 += zs[1][i]; }
    s0 += fcb[0]; s1 += fcb[1];
    float mx = fmaxf(s0, s1);
    float e0 = expf(s0-mx), e1 = expf(s1-mx);
    float den = e0 + e1;
    out[b*2+0] = e0/den;
    out[b*2+1] = e1/den;
  }
}

// ---------------------------------------------------------------------------
extern "C" void kernel_launch(void* const* d_in, const int* in_sizes, int n_in,
                              void* d_out, int out_size, void* d_ws, size_t ws_size,
                              hipStream_t stream)
{
  (void)in_sizes; (void)n_in; (void)out_size; (void)ws_size;
  const int*   sent   = (const int*)d_in[0];
  const float* att    = (const float*)d_in[1];
  const float* logits = (const float*)d_in[2];
  const float* mask   = (const float*)d_in[3];
  const float* wihf   = (const float*)d_in[4];
  const float* whhf   = (const float*)d_in[5];
  const float* bihf   = (const float*)d_in[6];
  const float* bhhf   = (const float*)d_in[7];
  const float* wihr   = (const float*)d_in[8];
  const float* whhr   = (const float*)d_in[9];
  const float* bihr   = (const float*)d_in[10];
  const float* bhhr   = (const float*)d_in[11];
  const float* fcw    = (const float*)d_in[12];
  const float* fcb    = (const float*)d_in[13];

  char* ws = (char*)d_ws;
  float*        rowsum  = (float*)(ws + 0);             // 393216
  int*          idxbuf  = (int*)(ws + 393216);          // 9216
  unsigned int* touched = (unsigned int*)(ws + 402432); // 32768
  float*        partial = (float*)(ws + 435200);        // 393216
  float*        rep     = (float*)(ws + 828416);        // 589824
  float*        biasf   = (float*)(ws + 1418240);       // 12288
  __bf16*       slide   = (__bf16*)(ws + 1430528);      // 3538944
  __bf16*       wcat    = (__bf16*)(ws + 4969472);      // 9437184
  __bf16*       whl2    = (__bf16*)(ws + 14406656);     // 2359296 (sliced+swizzled)
  float*        gx      = (float*)(ws + 16765952);      // 14155776
  __bf16*       h0      = (__bf16*)(ws + 30921728);     // 294912
  __bf16*       h1      = (__bf16*)(ws + 31216640);     // 294912
  float*        cbuf    = (float*)(ws + 31511552);      // 589824
  float*        hsbuf   = (float*)(ws + 32101376);      // 589824 -> end ~32.7 MB

  hipMemsetAsync(touched, 0, NB*NL2*sizeof(unsigned int), stream);
  prep_kernel<<<5187, 256, 0, stream>>>(wihf, wihr, whhf, whhr, bihf, bhhf, bihr, bhhr, wcat, whl2, biasf);
  rowsum_kernel<<<2048, 256, 0, stream>>>(att, sent, rowsum);
  master_kernel<<<NB*NH, 64, 0, stream>>>(rowsum, idxbuf, touched);
  slide_kernel<<<NROW, 192, 0, stream>>>(logits, mask, idxbuf, touched, slide);
  lrep_kernel<<<NB*8, 256, 0, stream>>>(logits, mask, touched, partial);
  gemm_kernel<<<216, 256, 0, stream>>>(slide, wcat, biasf, gx);
  lstm_step0_kernel<<<576, 256, 0, stream>>>(gx, h0, cbuf, hsbuf);
  __bf16* hbufs[2] = {h0, h1};
  for (int step=1; step<=5; ++step) {
    lstm_step_kernel<<<48, 256, 0, stream>>>(whl2, gx, hbufs[(step-1)&1], hbufs[step&1],
                                             cbuf, hsbuf, rep, step);
  }
  final_kernel<<<NB, 256, 0, stream>>>(rep, partial, fcw, fcb, (float*)d_out);
}